// Round 8
// baseline (952.884 us; speedup 1.0000x reference)
//
#include <hip/hip_runtime.h>
#include <cstdint>
#include <cmath>

#define NH 16
#define HD 64
#define SQ 2048
#define NB 4
#define DM 1024

typedef _Float16 half_t;
typedef _Float16 h8 __attribute__((ext_vector_type(8)));
typedef _Float16 h4 __attribute__((ext_vector_type(4)));
typedef _Float16 h2 __attribute__((ext_vector_type(2)));
typedef float f4 __attribute__((ext_vector_type(4)));

// bucket(delta) per MT5 relative_position_bucket (bidirectional, 32 buckets, max_dist 128)
__device__ __forceinline__ int rel_bucket(int delta) {
    int b = (delta > 0) ? 16 : 0;
    int a = (delta < 0) ? -delta : delta;
    if (a < 8) return b + a;
    int large = 8 + (int)(__logf((float)a * 0.125f) * 2.8853900817779268f);
    return b + (large < 15 ? large : 15);
}

// async global->LDS, 16B per lane; LDS dest = wave-uniform base + lane*16
__device__ __forceinline__ void gl_lds(const half_t* g, half_t* l) {
    __builtin_amdgcn_global_load_lds((const __attribute__((address_space(1))) unsigned int*)g,
                                     (__attribute__((address_space(3))) unsigned int*)l, 16, 0, 0);
}

__device__ __forceinline__ h2 pkrtz(float a, float b) {
    auto r = __builtin_amdgcn_cvt_pkrtz(a, b);
    return *(h2*)&r;
}

union PFU {
    h2 x[4];
    h8 v;
};

// ---- prep: X f32->f16 (0..4095) + W transposes (4096..5119) + dtab (5120..5135)
__global__ __launch_bounds__(256) void prep(const float* __restrict__ X,
                                            const float* __restrict__ Wq,
                                            const float* __restrict__ Wk,
                                            const float* __restrict__ Wv,
                                            const float* __restrict__ Wo,
                                            const float* __restrict__ table,
                                            half_t* __restrict__ Xh, half_t* __restrict__ Wqt,
                                            half_t* __restrict__ Wkt, half_t* __restrict__ Wvt,
                                            half_t* __restrict__ Wot, float* __restrict__ dtab) {
    const int id = blockIdx.x;
    if (id < 4096) {
        size_t i = ((size_t)id * 256 + threadIdx.x) * 8;
        float4 a = *(const float4*)&X[i];
        float4 b = *(const float4*)&X[i + 4];
        half_t t[8] = {(half_t)a.x, (half_t)a.y, (half_t)a.z, (half_t)a.w,
                       (half_t)b.x, (half_t)b.y, (half_t)b.z, (half_t)b.w};
        *(h8*)&Xh[i] = *(h8*)t;
        return;
    }
    if (id >= 5120) {
        const int h = id - 5120;  // dtab[h][d] = bias(delta = d - 2047) for head h
        for (int d = threadIdx.x; d < 4096; d += 256)
            dtab[h * 4096 + d] = table[rel_bucket(d - 2047) * NH + h];
        return;
    }
    __shared__ float T[64][65];
    const int t = id - 4096;
    const int which = t >> 8, tile = t & 255;
    const float* W = which == 0 ? Wq : which == 1 ? Wk : which == 2 ? Wv : Wo;
    half_t* Wt = which == 0 ? Wqt : which == 1 ? Wkt : which == 2 ? Wvt : Wot;
    const int k0 = (tile >> 4) * 64, n0 = (tile & 15) * 64;
    const int c = threadIdx.x & 63, rr = threadIdx.x >> 6;
    for (int r = rr; r < 64; r += 4) T[r][c] = W[(size_t)(k0 + r) * DM + n0 + c];
    __syncthreads();
    for (int r = rr; r < 64; r += 4) Wt[(size_t)(n0 + r) * DM + k0 + c] = (half_t)T[c][r];
}

// ---- v[bh][s][d] f16 -> vT[bh][d][s] f16 ------------------------------------
__global__ __launch_bounds__(256) void transpose_v(const half_t* __restrict__ v,
                                                   half_t* __restrict__ vT) {
    __shared__ half_t T[64][72];
    const int bh = blockIdx.y, j0 = blockIdx.x * 64;
    const size_t base = (size_t)bh * (SQ * HD);
    const int t = threadIdx.x;
    for (int e = t; e < 512; e += 256) {
        int r = e >> 3, c = e & 7;
        *(h8*)&T[r][c * 8] = *(const h8*)&v[base + (size_t)(j0 + r) * HD + c * 8];
    }
    __syncthreads();
    const int d = t & 63, jc = t >> 6;
    half_t tmp[16];
#pragma unroll
    for (int jj = 0; jj < 16; ++jj) tmp[jj] = T[jc * 16 + jj][d];
    *(h8*)&vT[base + (size_t)d * SQ + j0 + jc * 16] = *(h8*)&tmp[0];
    *(h8*)&vT[base + (size_t)d * SQ + j0 + jc * 16 + 8] = *(h8*)&tmp[8];
}

// ---- QKV MFMA GEMM: dbuf LDS, swapped-operand epilogue (reg dim = n) --------
__global__ __launch_bounds__(256) void mm_qkv(const half_t* __restrict__ A,
                                              const half_t* __restrict__ Wqt,
                                              const half_t* __restrict__ Wkt,
                                              const half_t* __restrict__ Wvt,
                                              half_t* __restrict__ qo, half_t* __restrict__ ko,
                                              half_t* __restrict__ vo) {
    const int z = blockIdx.z;
    const half_t* Bt = z == 0 ? Wqt : z == 1 ? Wkt : Wvt;
    half_t* outp = z == 0 ? qo : z == 1 ? ko : vo;
    __shared__ half_t Al[2][4096];
    __shared__ half_t Bl[2][4096];
    const int tid = threadIdx.x;
    const int lane = tid & 63, w = tid >> 6;
    const int wr = w >> 1, wc = w & 1;
    const int id0 = blockIdx.y * 8 + blockIdx.x;
    const int swz = (id0 & 7) * 64 + (id0 >> 3);
    const int m0 = (swz >> 3) * 128, n0 = (swz & 7) * 128;

    f4 acc[4][4];
#pragma unroll
    for (int i = 0; i < 4; ++i)
#pragma unroll
        for (int j = 0; j < 4; ++j) acc[i][j] = (f4){0.f, 0.f, 0.f, 0.f};

    const int kc = lane >> 4;
    const int srl = lane >> 2;
    const int sc = lane & 3;

    auto stage = [&](int buf, int k0) {
#pragma unroll
        for (int inst = 0; inst < 2; ++inst) {
            int r = w * 32 + inst * 16 + srl;
            int cg = sc ^ ((r >> 1) & 3);
            gl_lds(&A[(size_t)(m0 + r) * DM + k0 + cg * 8], &Al[buf][(w * 32 + inst * 16) * 32]);
            gl_lds(&Bt[(size_t)(n0 + r) * DM + k0 + cg * 8], &Bl[buf][(w * 32 + inst * 16) * 32]);
        }
    };

    stage(0, 0);
    __syncthreads();
    int cur = 0;
    for (int t = 0; t < 32; ++t) {
        if (t < 31) stage(cur ^ 1, (t + 1) * 32);
        h8 af[4], bf[4];
#pragma unroll
        for (int ms = 0; ms < 4; ++ms) {
            int r = wr * 64 + ms * 16 + (lane & 15);
            af[ms] = *(const h8*)&Al[cur][r * 32 + ((kc ^ ((r >> 1) & 3)) * 8)];
        }
#pragma unroll
        for (int ns = 0; ns < 4; ++ns) {
            int r = wc * 64 + ns * 16 + (lane & 15);
            bf[ns] = *(const h8*)&Bl[cur][r * 32 + ((kc ^ ((r >> 1) & 3)) * 8)];
        }
        // swapped operands: C col (lane&15) = m, reg dim = n
#pragma unroll
        for (int ms = 0; ms < 4; ++ms)
#pragma unroll
            for (int ns = 0; ns < 4; ++ns)
                acc[ms][ns] =
                    __builtin_amdgcn_mfma_f32_16x16x32_f16(bf[ns], af[ms], acc[ms][ns], 0, 0, 0);
        __syncthreads();
        cur ^= 1;
    }

#pragma unroll
    for (int ms = 0; ms < 4; ++ms)
#pragma unroll
        for (int ns = 0; ns < 4; ++ns) {
            int m = m0 + wr * 64 + ms * 16 + (lane & 15);
            int nb = n0 + wc * 64 + ns * 16 + ((lane >> 4) << 2);
            int b = m >> 11, s = m & 2047, h = nb >> 6, d = nb & 63;
            h4 ph = {(half_t)acc[ms][ns][0], (half_t)acc[ms][ns][1], (half_t)acc[ms][ns][2],
                     (half_t)acc[ms][ns][3]};
            *(h4*)&outp[((size_t)(b * NH + h) * SQ + s) * HD + d] = ph;
        }
}

// ---- Wo GEMM: dbuf LDS, swapped-operand epilogue, f4 nt stores --------------
__global__ __launch_bounds__(256) void mm_wo(const half_t* __restrict__ A,
                                             const half_t* __restrict__ Bt,
                                             float* __restrict__ outp) {
    __shared__ half_t Al[2][4096];
    __shared__ half_t Bl[2][4096];
    const int tid = threadIdx.x;
    const int lane = tid & 63, w = tid >> 6;
    const int wr = w >> 1, wc = w & 1;
    const int id0 = blockIdx.y * 8 + blockIdx.x;
    const int swz = (id0 & 7) * 64 + (id0 >> 3);
    const int m0 = (swz >> 3) * 128, n0 = (swz & 7) * 128;

    f4 acc[4][4];
#pragma unroll
    for (int i = 0; i < 4; ++i)
#pragma unroll
        for (int j = 0; j < 4; ++j) acc[i][j] = (f4){0.f, 0.f, 0.f, 0.f};

    const int kc = lane >> 4;
    const int srl = lane >> 2;
    const int sc = lane & 3;

    auto stage = [&](int buf, int k0) {
#pragma unroll
        for (int inst = 0; inst < 2; ++inst) {
            int r = w * 32 + inst * 16 + srl;
            int cg = sc ^ ((r >> 1) & 3);
            gl_lds(&A[(size_t)(m0 + r) * DM + k0 + cg * 8], &Al[buf][(w * 32 + inst * 16) * 32]);
            gl_lds(&Bt[(size_t)(n0 + r) * DM + k0 + cg * 8], &Bl[buf][(w * 32 + inst * 16) * 32]);
        }
    };

    stage(0, 0);
    __syncthreads();
    int cur = 0;
    for (int t = 0; t < 32; ++t) {
        if (t < 31) stage(cur ^ 1, (t + 1) * 32);
        h8 af[4], bf[4];
#pragma unroll
        for (int ms = 0; ms < 4; ++ms) {
            int r = wr * 64 + ms * 16 + (lane & 15);
            af[ms] = *(const h8*)&Al[cur][r * 32 + ((kc ^ ((r >> 1) & 3)) * 8)];
        }
#pragma unroll
        for (int ns = 0; ns < 4; ++ns) {
            int r = wc * 64 + ns * 16 + (lane & 15);
            bf[ns] = *(const h8*)&Bl[cur][r * 32 + ((kc ^ ((r >> 1) & 3)) * 8)];
        }
#pragma unroll
        for (int ms = 0; ms < 4; ++ms)
#pragma unroll
            for (int ns = 0; ns < 4; ++ns)
                acc[ms][ns] =
                    __builtin_amdgcn_mfma_f32_16x16x32_f16(bf[ns], af[ms], acc[ms][ns], 0, 0, 0);
        __syncthreads();
        cur ^= 1;
    }

#pragma unroll
    for (int ms = 0; ms < 4; ++ms)
#pragma unroll
        for (int ns = 0; ns < 4; ++ns) {
            int m = m0 + wr * 64 + ms * 16 + (lane & 15);
            int nb = n0 + wc * 64 + ns * 16 + ((lane >> 4) << 2);
            __builtin_nontemporal_store(acc[ms][ns], (f4*)&outp[(size_t)m * DM + nb]);
        }
}

// ---- fused attention: pi-permuted K rows -> in-register P (no P-LDS) --------
// block = 128 q-rows of one (b,h); 4 waves x 32 rows; LDS 41.5 KB.
__global__ __launch_bounds__(256) void fused_attn(const half_t* __restrict__ q,
                                                  const half_t* __restrict__ k,
                                                  const half_t* __restrict__ vT,
                                                  const float* __restrict__ dtab,
                                                  float* __restrict__ attw,
                                                  half_t* __restrict__ ctx) {
    __shared__ float biasE[2176];   // exp(bias(delta)), u = j - il + 127
    __shared__ half_t Kl[2][4096];  // K tile dbuf: slot s of row r = chunk s ^ f(r)
    __shared__ half_t Vl[2][4096];  // V^T tile dbuf: same swizzle
    const int tid = threadIdx.x, lane = tid & 63, w = tid >> 6;

    const int id = blockIdx.x;
    const int idx = (id & 7) * 128 + (id >> 3);
    const int bh = idx >> 4, i0 = (idx & 15) * 128;
    const int h = bh & 15, b = bh >> 4;
    const size_t qb = (size_t)bh * (SQ * HD);
    const half_t* kb = k + qb;
    const half_t* vb = vT + qb;

    for (int t = tid; t < 2176; t += 256) biasE[t] = __expf(dtab[h * 4096 + t - i0 + 1920]);

    h8 qf[2][2];
#pragma unroll
    for (int isub = 0; isub < 2; ++isub) {
        const half_t* qp =
            &q[qb + (size_t)(i0 + w * 32 + isub * 16 + (lane & 15)) * HD + (lane >> 4) * 8];
        qf[isub][0] = *(const h8*)qp;
        qf[isub][1] = *(const h8*)(qp + 32);
    }

    const int sr = lane >> 3;  // staging row within 8-row group
    const int sc = lane & 7;   // staging slot
    const int kc = lane >> 4;
    // f(r) = ((r>>3)&1)*4 + (r&3); specialized per access pattern:
    const int f_s0 = 0 + ((lane >> 3) & 3);                 // staging inst=0
    const int f_s1 = 4 + ((lane >> 3) & 3);                 // staging inst=1
    const int f_k = (((lane >> 2) & 1) << 2) + (lane & 3);  // pi-rows (K frags)
    const int f_v = (((lane >> 3) & 1) << 2) + (lane & 3);  // consecutive rows (V frags)
    // pi row base: rbase = ((lane&15)>>2)*8 + (lane&3)
    const int rb64 = ((((lane & 15) >> 2) << 3) + (lane & 3)) << 6;

    auto stageK = [&](int buf, int j0) {
        int r0 = w * 16 + sr;
        gl_lds(&kb[(size_t)(j0 + r0) * HD + ((sc ^ f_s0) * 8)], &Kl[buf][(w * 16) * 64]);
        gl_lds(&kb[(size_t)(j0 + r0 + 8) * HD + ((sc ^ f_s1) * 8)], &Kl[buf][(w * 16 + 8) * 64]);
    };
    auto stageV = [&](int buf, int j0) {
        int r0 = w * 16 + sr;
        gl_lds(&vb[(size_t)r0 * SQ + j0 + ((sc ^ f_s0) * 8)], &Vl[buf][(w * 16) * 64]);
        gl_lds(&vb[(size_t)(r0 + 8) * SQ + j0 + ((sc ^ f_s1) * 8)], &Vl[buf][(w * 16 + 8) * 64]);
    };

    const int il0 = w * 32 + (lane & 15);  // + isub*16
    const int c8 = (lane >> 4) << 3;       // c*8

    // ---- pass 1: row sums of exp(score)*exp(bias) ---------------------------
    stageK(0, 0);
    __syncthreads();
    float srow[2] = {0.f, 0.f};
    int cur = 0;
    for (int t = 0; t < 32; ++t) {
        const int j0 = t * 64;
        if (t < 31) stageK(cur ^ 1, j0 + 64);
#pragma unroll
        for (int ns = 0; ns < 4; ++ns) {
            const int roff = rb64 + (((ns >> 1) * 32 + (ns & 1) * 4) << 6);
            h8 kf0 = *(const h8*)&Kl[cur][roff + ((kc ^ f_k) * 8)];
            h8 kf1 = *(const h8*)&Kl[cur][roff + (((kc + 4) ^ f_k) * 8)];
#pragma unroll
            for (int isub = 0; isub < 2; ++isub) {
                f4 z = (f4){0.f, 0.f, 0.f, 0.f};
                z = __builtin_amdgcn_mfma_f32_16x16x32_f16(kf0, qf[isub][0], z, 0, 0, 0);
                z = __builtin_amdgcn_mfma_f32_16x16x32_f16(kf1, qf[isub][1], z, 0, 0, 0);
                const int u0 = j0 + (ns >> 1) * 32 + c8 + (ns & 1) * 4 - (il0 + isub * 16) + 127;
#pragma unroll
                for (int reg = 0; reg < 4; ++reg)
                    srow[isub] = fmaf(__expf(z[reg]), biasE[u0 + reg], srow[isub]);
            }
        }
        __syncthreads();
        cur ^= 1;
    }
    float sinv[2];
#pragma unroll
    for (int isub = 0; isub < 2; ++isub) {
        float s = srow[isub];
        s += __shfl_xor(s, 16);
        s += __shfl_xor(s, 32);
        sinv[isub] = 1.0f / s;
    }

    // ---- pass 2: recompute, nt f4 attw writes, in-register P, PV ------------
    f4 o[4][2];
#pragma unroll
    for (int ns = 0; ns < 4; ++ns)
#pragma unroll
        for (int isub = 0; isub < 2; ++isub) o[ns][isub] = (f4){0.f, 0.f, 0.f, 0.f};
    const size_t awb = (size_t)bh * ((size_t)SQ * SQ);

    stageK(0, 0);
    stageV(0, 0);
    __syncthreads();
    cur = 0;
    for (int t = 0; t < 32; ++t) {
        const int j0 = t * 64;
        if (t < 31) {
            stageK(cur ^ 1, j0 + 64);
            stageV(cur ^ 1, j0 + 64);
        }
        __builtin_amdgcn_sched_barrier(0);  // pin: staging loads issue before attw stores
        PFU pf[2][2];
#pragma unroll
        for (int ns = 0; ns < 4; ++ns) {
            const int roff = rb64 + (((ns >> 1) * 32 + (ns & 1) * 4) << 6);
            h8 kf0 = *(const h8*)&Kl[cur][roff + ((kc ^ f_k) * 8)];
            h8 kf1 = *(const h8*)&Kl[cur][roff + (((kc + 4) ^ f_k) * 8)];
#pragma unroll
            for (int isub = 0; isub < 2; ++isub) {
                f4 z = (f4){0.f, 0.f, 0.f, 0.f};
                z = __builtin_amdgcn_mfma_f32_16x16x32_f16(kf0, qf[isub][0], z, 0, 0, 0);
                z = __builtin_amdgcn_mfma_f32_16x16x32_f16(kf1, qf[isub][1], z, 0, 0, 0);
                const int jl = (ns >> 1) * 32 + c8 + (ns & 1) * 4;
                const int u0 = j0 + jl - (il0 + isub * 16) + 127;
                f4 p;
#pragma unroll
                for (int reg = 0; reg < 4; ++reg)
                    p[reg] = __expf(z[reg]) * biasE[u0 + reg] * sinv[isub];
                __builtin_nontemporal_store(
                    p, (f4*)&attw[awb + (size_t)(i0 + il0 + isub * 16) * SQ + j0 + jl]);
                pf[isub][ns >> 1].x[(ns & 1) * 2 + 0] = pkrtz(p[0], p[1]);
                pf[isub][ns >> 1].x[(ns & 1) * 2 + 1] = pkrtz(p[2], p[3]);
            }
        }
#pragma unroll
        for (int ns = 0; ns < 4; ++ns) {
            const int rr = ns * 16 + (lane & 15);
            h8 vf0 = *(const h8*)&Vl[cur][rr * 64 + ((kc ^ f_v) * 8)];
            h8 vf1 = *(const h8*)&Vl[cur][rr * 64 + (((kc + 4) ^ f_v) * 8)];
#pragma unroll
            for (int isub = 0; isub < 2; ++isub) {
                o[ns][isub] = __builtin_amdgcn_mfma_f32_16x16x32_f16(pf[isub][0].v, vf0,
                                                                    o[ns][isub], 0, 0, 0);
                o[ns][isub] = __builtin_amdgcn_mfma_f32_16x16x32_f16(pf[isub][1].v, vf1,
                                                                    o[ns][isub], 0, 0, 0);
            }
        }
        // counted wait: the 4 staging loads are the oldest vmem ops; the 8 nt
        // attw stores issued after them may stay in flight across the barrier.
        asm volatile("s_waitcnt vmcnt(8)" ::: "memory");
        __builtin_amdgcn_s_barrier();
        __builtin_amdgcn_sched_barrier(0);
        cur ^= 1;
    }
#pragma unroll
    for (int ns = 0; ns < 4; ++ns)
#pragma unroll
        for (int isub = 0; isub < 2; ++isub)
#pragma unroll
            for (int reg = 0; reg < 4; ++reg) {
                int row = i0 + w * 32 + isub * 16 + (lane >> 4) * 4 + reg;
                int d = ns * 16 + (lane & 15);
                ctx[((size_t)(b * SQ + row)) * DM + h * HD + d] = (half_t)o[ns][isub][reg];
            }
}

// ---- position_bias fill: pure streaming from delta table --------------------
__global__ __launch_bounds__(256) void bias_fill(const float* __restrict__ dtab,
                                                 float* __restrict__ pb) {
    __shared__ float L[2052];
    const int i = blockIdx.x, h = blockIdx.y;
    const int s0 = 2047 - i, a0 = s0 & ~3, sh = s0 - a0;
    for (int t = threadIdx.x * 4; t < 2052; t += 1024)
        *(f4*)&L[t] = *(const f4*)&dtab[h * 4096 + a0 + t];
    __syncthreads();
    const size_t base = ((size_t)h * SQ + i) * SQ;
#pragma unroll
    for (int half = 0; half < 2; ++half) {
        int j = half * 1024 + threadIdx.x * 4;
        f4 o = {L[sh + j], L[sh + j + 1], L[sh + j + 2], L[sh + j + 3]};
        __builtin_nontemporal_store(o, (f4*)&pb[base + j]);
    }
}

extern "C" void kernel_launch(void* const* d_in, const int* in_sizes, int n_in, void* d_out,
                              int out_size, void* d_ws, size_t ws_size, hipStream_t stream) {
    const float* X = (const float*)d_in[0];
    const float* Wq = (const float*)d_in[1];
    const float* Wk = (const float*)d_in[2];
    const float* Wv = (const float*)d_in[3];
    const float* Wo = (const float*)d_in[4];
    const float* tbl = (const float*)d_in[5];

    float* out = (float*)d_out;
    float* attn_out = out;                    // 8,388,608 f32
    float* pb = out + (size_t)NB * SQ * DM;   // 67,108,864 f32
    float* attw = pb + (size_t)NH * SQ * SQ;  // 268,435,456 f32

    // f16 scratch: prefer d_ws; fall back to pb region (bias_fill overwrites LAST)
    const size_t need_bytes = 109314048;
    half_t* hb = (ws_size >= need_bytes) ? (half_t*)d_ws : (half_t*)pb;
    half_t* Xh = hb;
    half_t* qh = hb + 8388608;
    half_t* kh = hb + 16777216;
    half_t* vh = hb + 25165824;
    half_t* vTh = hb + 33554432;
    half_t* ctxh = hb + 41943040;
    half_t* Wqt = hb + 50331648;
    half_t* Wkt = hb + 51380224;
    half_t* Wvt = hb + 52428800;
    half_t* Wot = hb + 53477376;
    float* dtab = (float*)(hb + 54525952);  // 16 x 4096 f32

    dim3 blk(256);
    prep<<<dim3(5136), blk, 0, stream>>>(X, Wq, Wk, Wv, Wo, tbl, Xh, Wqt, Wkt, Wvt, Wot, dtab);
    mm_qkv<<<dim3(8, 64, 3), blk, 0, stream>>>(Xh, Wqt, Wkt, Wvt, qh, kh, vh);
    transpose_v<<<dim3(32, 64), blk, 0, stream>>>(vh, vTh);
    fused_attn<<<dim3(1024), blk, 0, stream>>>(qh, kh, vTh, dtab, attw, ctxh);
    mm_wo<<<dim3(8, 64), blk, 0, stream>>>(ctxh, Wot, attn_out);
    bias_fill<<<dim3(SQ, NH), blk, 0, stream>>>(dtab, pb);
}

// Round 9
// 593.930 us; speedup vs baseline: 1.6044x; 1.6044x over previous
//
#include <hip/hip_runtime.h>
#include <cstdint>
#include <cmath>

#define NH 16
#define HD 64
#define SQ 2048
#define NB 4
#define DM 1024

typedef _Float16 half_t;
typedef _Float16 h8 __attribute__((ext_vector_type(8)));
typedef _Float16 h4 __attribute__((ext_vector_type(4)));
typedef float f4 __attribute__((ext_vector_type(4)));

// bucket(delta) per MT5 relative_position_bucket (bidirectional, 32 buckets, max_dist 128)
__device__ __forceinline__ int rel_bucket(int delta) {
    int b = (delta > 0) ? 16 : 0;
    int a = (delta < 0) ? -delta : delta;
    if (a < 8) return b + a;
    int large = 8 + (int)(__logf((float)a * 0.125f) * 2.8853900817779268f);
    return b + (large < 15 ? large : 15);
}

// async global->LDS, 16B per lane; LDS dest = wave-uniform base + lane*16
__device__ __forceinline__ void gl_lds(const half_t* g, half_t* l) {
    __builtin_amdgcn_global_load_lds((const __attribute__((address_space(1))) unsigned int*)g,
                                     (__attribute__((address_space(3))) unsigned int*)l, 16, 0, 0);
}

// ---- prep: X f32->f16 (0..4095) + W transposes (4096..5119) + dtab (5120..5135)
__global__ __launch_bounds__(256) void prep(const float* __restrict__ X,
                                            const float* __restrict__ Wq,
                                            const float* __restrict__ Wk,
                                            const float* __restrict__ Wv,
                                            const float* __restrict__ Wo,
                                            const float* __restrict__ table,
                                            half_t* __restrict__ Xh, half_t* __restrict__ Wqt,
                                            half_t* __restrict__ Wkt, half_t* __restrict__ Wvt,
                                            half_t* __restrict__ Wot, float* __restrict__ dtab) {
    const int id = blockIdx.x;
    if (id < 4096) {
        size_t i = ((size_t)id * 256 + threadIdx.x) * 8;
        float4 a = *(const float4*)&X[i];
        float4 b = *(const float4*)&X[i + 4];
        half_t t[8] = {(half_t)a.x, (half_t)a.y, (half_t)a.z, (half_t)a.w,
                       (half_t)b.x, (half_t)b.y, (half_t)b.z, (half_t)b.w};
        *(h8*)&Xh[i] = *(h8*)t;
        return;
    }
    if (id >= 5120) {
        const int h = id - 5120;  // dtab[h][d] = bias(delta = d - 2047) for head h
        for (int d = threadIdx.x; d < 4096; d += 256)
            dtab[h * 4096 + d] = table[rel_bucket(d - 2047) * NH + h];
        return;
    }
    __shared__ float T[64][65];
    const int t = id - 4096;
    const int which = t >> 8, tile = t & 255;
    const float* W = which == 0 ? Wq : which == 1 ? Wk : which == 2 ? Wv : Wo;
    half_t* Wt = which == 0 ? Wqt : which == 1 ? Wkt : which == 2 ? Wvt : Wot;
    const int k0 = (tile >> 4) * 64, n0 = (tile & 15) * 64;
    const int c = threadIdx.x & 63, rr = threadIdx.x >> 6;
    for (int r = rr; r < 64; r += 4) T[r][c] = W[(size_t)(k0 + r) * DM + n0 + c];
    __syncthreads();
    for (int r = rr; r < 64; r += 4) Wt[(size_t)(n0 + r) * DM + k0 + c] = (half_t)T[c][r];
}

// ---- QKV MFMA GEMM: z=0,1 -> q/k scatter [bh][s][d]; z=2 -> V^T direct [bh][d][s]
__global__ __launch_bounds__(256) void mm_qkv(const half_t* __restrict__ A,
                                              const half_t* __restrict__ Wqt,
                                              const half_t* __restrict__ Wkt,
                                              const half_t* __restrict__ Wvt,
                                              half_t* __restrict__ qo, half_t* __restrict__ ko,
                                              half_t* __restrict__ vTo) {
    const int z = blockIdx.z;
    const half_t* Bt = z == 0 ? Wqt : (z == 1 ? Wkt : Wvt);
    __shared__ half_t Al[2][4096];
    __shared__ half_t Bl[2][4096];
    const int tid = threadIdx.x;
    const int lane = tid & 63, w = tid >> 6;
    const int wr = w >> 1, wc = w & 1;
    const int id0 = blockIdx.y * 8 + blockIdx.x;
    const int swz = (id0 & 7) * 64 + (id0 >> 3);
    const int m0 = (swz >> 3) * 128, n0 = (swz & 7) * 128;

    const int kc = lane >> 4;
    const int srl = lane >> 2;
    const int sc = lane & 3;

    auto stage = [&](int buf, int k0) {
#pragma unroll
        for (int inst = 0; inst < 2; ++inst) {
            int r = w * 32 + inst * 16 + srl;
            int cg = sc ^ ((r >> 1) & 3);
            gl_lds(&A[(size_t)(m0 + r) * DM + k0 + cg * 8], &Al[buf][(w * 32 + inst * 16) * 32]);
            gl_lds(&Bt[(size_t)(n0 + r) * DM + k0 + cg * 8], &Bl[buf][(w * 32 + inst * 16) * 32]);
        }
    };

    f4 acc[4][4];
#pragma unroll
    for (int i = 0; i < 4; ++i)
#pragma unroll
        for (int j = 0; j < 4; ++j) acc[i][j] = (f4){0.f, 0.f, 0.f, 0.f};

    stage(0, 0);
    __syncthreads();
    int cur = 0;
    if (z < 2) {
        // swapped operands: C reg dim = n (4 consec) -> h4 scatter stores
        for (int t = 0; t < 32; ++t) {
            if (t < 31) stage(cur ^ 1, (t + 1) * 32);
            h8 af[4], bf[4];
#pragma unroll
            for (int ms = 0; ms < 4; ++ms) {
                int r = wr * 64 + ms * 16 + (lane & 15);
                af[ms] = *(const h8*)&Al[cur][r * 32 + ((kc ^ ((r >> 1) & 3)) * 8)];
            }
#pragma unroll
            for (int ns = 0; ns < 4; ++ns) {
                int r = wc * 64 + ns * 16 + (lane & 15);
                bf[ns] = *(const h8*)&Bl[cur][r * 32 + ((kc ^ ((r >> 1) & 3)) * 8)];
            }
#pragma unroll
            for (int ms = 0; ms < 4; ++ms)
#pragma unroll
                for (int ns = 0; ns < 4; ++ns)
                    acc[ms][ns] = __builtin_amdgcn_mfma_f32_16x16x32_f16(bf[ns], af[ms],
                                                                         acc[ms][ns], 0, 0, 0);
            __syncthreads();
            cur ^= 1;
        }
        half_t* outp = z == 0 ? qo : ko;
#pragma unroll
        for (int ms = 0; ms < 4; ++ms)
#pragma unroll
            for (int ns = 0; ns < 4; ++ns) {
                int m = m0 + wr * 64 + ms * 16 + (lane & 15);
                int nb = n0 + wc * 64 + ns * 16 + ((lane >> 4) << 2);
                int b = m >> 11, s = m & 2047, h = nb >> 6, d = nb & 63;
                h4 ph = {(half_t)acc[ms][ns][0], (half_t)acc[ms][ns][1], (half_t)acc[ms][ns][2],
                         (half_t)acc[ms][ns][3]};
                *(h4*)&outp[((size_t)(b * NH + h) * SQ + s) * HD + d] = ph;
            }
    } else {
        // normal operands: C reg dim = m = s (4 consec) -> h4 stores along vT rows
        for (int t = 0; t < 32; ++t) {
            if (t < 31) stage(cur ^ 1, (t + 1) * 32);
            h8 af[4], bf[4];
#pragma unroll
            for (int ms = 0; ms < 4; ++ms) {
                int r = wr * 64 + ms * 16 + (lane & 15);
                af[ms] = *(const h8*)&Al[cur][r * 32 + ((kc ^ ((r >> 1) & 3)) * 8)];
            }
#pragma unroll
            for (int ns = 0; ns < 4; ++ns) {
                int r = wc * 64 + ns * 16 + (lane & 15);
                bf[ns] = *(const h8*)&Bl[cur][r * 32 + ((kc ^ ((r >> 1) & 3)) * 8)];
            }
#pragma unroll
            for (int ms = 0; ms < 4; ++ms)
#pragma unroll
                for (int ns = 0; ns < 4; ++ns)
                    acc[ms][ns] = __builtin_amdgcn_mfma_f32_16x16x32_f16(af[ms], bf[ns],
                                                                         acc[ms][ns], 0, 0, 0);
            __syncthreads();
            cur ^= 1;
        }
#pragma unroll
        for (int ms = 0; ms < 4; ++ms)
#pragma unroll
            for (int ns = 0; ns < 4; ++ns) {
                int s = m0 + wr * 64 + ms * 16 + ((lane >> 4) << 2);
                int nb = n0 + wc * 64 + ns * 16 + (lane & 15);
                int b = s >> 11, sl = s & 2047, h = nb >> 6, d = nb & 63;
                h4 ph = {(half_t)acc[ms][ns][0], (half_t)acc[ms][ns][1], (half_t)acc[ms][ns][2],
                         (half_t)acc[ms][ns][3]};
                *(h4*)&vTo[((size_t)(b * NH + h) * HD + d) * SQ + sl] = ph;
            }
    }
}

// ---- Wo GEMM: dbuf LDS, swapped-operand epilogue, f4 nt stores --------------
__global__ __launch_bounds__(256) void mm_wo(const half_t* __restrict__ A,
                                             const half_t* __restrict__ Bt,
                                             float* __restrict__ outp) {
    __shared__ half_t Al[2][4096];
    __shared__ half_t Bl[2][4096];
    const int tid = threadIdx.x;
    const int lane = tid & 63, w = tid >> 6;
    const int wr = w >> 1, wc = w & 1;
    const int id0 = blockIdx.y * 8 + blockIdx.x;
    const int swz = (id0 & 7) * 64 + (id0 >> 3);
    const int m0 = (swz >> 3) * 128, n0 = (swz & 7) * 128;

    f4 acc[4][4];
#pragma unroll
    for (int i = 0; i < 4; ++i)
#pragma unroll
        for (int j = 0; j < 4; ++j) acc[i][j] = (f4){0.f, 0.f, 0.f, 0.f};

    const int kc = lane >> 4;
    const int srl = lane >> 2;
    const int sc = lane & 3;

    auto stage = [&](int buf, int k0) {
#pragma unroll
        for (int inst = 0; inst < 2; ++inst) {
            int r = w * 32 + inst * 16 + srl;
            int cg = sc ^ ((r >> 1) & 3);
            gl_lds(&A[(size_t)(m0 + r) * DM + k0 + cg * 8], &Al[buf][(w * 32 + inst * 16) * 32]);
            gl_lds(&Bt[(size_t)(n0 + r) * DM + k0 + cg * 8], &Bl[buf][(w * 32 + inst * 16) * 32]);
        }
    };

    stage(0, 0);
    __syncthreads();
    int cur = 0;
    for (int t = 0; t < 32; ++t) {
        if (t < 31) stage(cur ^ 1, (t + 1) * 32);
        h8 af[4], bf[4];
#pragma unroll
        for (int ms = 0; ms < 4; ++ms) {
            int r = wr * 64 + ms * 16 + (lane & 15);
            af[ms] = *(const h8*)&Al[cur][r * 32 + ((kc ^ ((r >> 1) & 3)) * 8)];
        }
#pragma unroll
        for (int ns = 0; ns < 4; ++ns) {
            int r = wc * 64 + ns * 16 + (lane & 15);
            bf[ns] = *(const h8*)&Bl[cur][r * 32 + ((kc ^ ((r >> 1) & 3)) * 8)];
        }
#pragma unroll
        for (int ms = 0; ms < 4; ++ms)
#pragma unroll
            for (int ns = 0; ns < 4; ++ns)
                acc[ms][ns] =
                    __builtin_amdgcn_mfma_f32_16x16x32_f16(bf[ns], af[ms], acc[ms][ns], 0, 0, 0);
        __syncthreads();
        cur ^= 1;
    }

#pragma unroll
    for (int ms = 0; ms < 4; ++ms)
#pragma unroll
        for (int ns = 0; ns < 4; ++ns) {
            int m = m0 + wr * 64 + ms * 16 + (lane & 15);
            int nb = n0 + wc * 64 + ns * 16 + ((lane >> 4) << 2);
            __builtin_nontemporal_store(acc[ms][ns], (f4*)&outp[(size_t)m * DM + nb]);
        }
}

// ---- fused attention: R6 structure (LDS-P), raw-bias exp fusion, pb fused ---
// block = 128 q-rows of one (b,h); 4 waves x 32 rows; LDS 48 KB -> 3 blocks/CU.
__global__ __launch_bounds__(256) void fused_attn(const half_t* __restrict__ q,
                                                  const half_t* __restrict__ k,
                                                  const half_t* __restrict__ vT,
                                                  const float* __restrict__ dtab,
                                                  float* __restrict__ attw,
                                                  half_t* __restrict__ ctx,
                                                  float* __restrict__ pbp) {
    __shared__ float dtabL[4096];   // raw bias(delta), idx u = j - i + 2047
    __shared__ char Psm[16384];     // per-wave 4KB: P[32 i][64 j] f16, 16B-slot XOR swizzle
    __shared__ half_t Kl[4096];     // K tile: slot s of row r = chunk s^(r&7)
    __shared__ half_t Vl[4096];     // V^T tile: same swizzle
    const int tid = threadIdx.x, lane = tid & 63, w = tid >> 6;

    // XCD-bijective swizzle: each bh's 16 blocks on one XCD
    const int id = blockIdx.x;
    const int idx = (id & 7) * 128 + (id >> 3);
    const int bh = idx >> 4, i0 = (idx & 15) * 128;
    const int h = bh & 15, b = bh >> 4;
    const size_t qb = (size_t)bh * (SQ * HD);
    const half_t* kb = k + qb;
    const half_t* vb = vT + qb;

    for (int t = tid * 4; t < 4096; t += 1024)
        *(f4*)&dtabL[t] = *(const f4*)&dtab[h * 4096 + t];

    h8 qf[2][2];
#pragma unroll
    for (int isub = 0; isub < 2; ++isub) {
        const half_t* qp =
            &q[qb + (size_t)(i0 + w * 32 + isub * 16 + (lane & 15)) * HD + (lane >> 4) * 8];
        qf[isub][0] = *(const h8*)qp;
        qf[isub][1] = *(const h8*)(qp + 32);
    }

    const int sr = lane >> 3;  // staging row within 8-row group
    const int sc = lane & 7;   // LDS slot

    auto stageK = [&](int j0) {
#pragma unroll
        for (int inst = 0; inst < 2; ++inst) {
            int r = w * 16 + inst * 8 + sr;
            gl_lds(&kb[(size_t)(j0 + r) * HD + ((sc ^ (r & 7)) * 8)], &Kl[(w * 16 + inst * 8) * 64]);
        }
    };
    auto stageV = [&](int j0) {
#pragma unroll
        for (int inst = 0; inst < 2; ++inst) {
            int r = w * 16 + inst * 8 + sr;
            gl_lds(&vb[(size_t)r * SQ + j0 + ((sc ^ (r & 7)) * 8)], &Vl[(w * 16 + inst * 8) * 64]);
        }
    };

    // ---- pass 1: row sums of exp(score + bias); pb rows written here --------
    float srow[2] = {0.f, 0.f};
    for (int t = 0; t < 32; ++t) {
        const int j0 = t * 64;
        stageK(j0);
        __syncthreads();
#pragma unroll
        for (int ns = 0; ns < 4; ++ns) {
            const int rr = ns * 16 + (lane & 15);
            const int kc = lane >> 4;
            h8 kf0 = *(const h8*)&Kl[rr * 64 + ((kc ^ (rr & 7)) * 8)];
            h8 kf1 = *(const h8*)&Kl[rr * 64 + (((kc + 4) ^ (rr & 7)) * 8)];
#pragma unroll
            for (int isub = 0; isub < 2; ++isub) {
                f4 z = (f4){0.f, 0.f, 0.f, 0.f};
                z = __builtin_amdgcn_mfma_f32_16x16x32_f16(kf0, qf[isub][0], z, 0, 0, 0);
                z = __builtin_amdgcn_mfma_f32_16x16x32_f16(kf1, qf[isub][1], z, 0, 0, 0);
                const int u0 = j0 + ns * 16 + ((lane >> 4) << 2) -
                               (i0 + w * 32 + isub * 16 + (lane & 15)) + 2047;
#pragma unroll
                for (int reg = 0; reg < 4; ++reg)
                    srow[isub] += __expf(z[reg] + dtabL[u0 + reg]);
            }
        }
        // fused position_bias row write: row r = i0 + b*32 + t
        if (pbp) {
            const int r = i0 + b * 32 + t;
            const int bu = 2047 - r;
            const int j8 = tid * 8;
            f4 o0 = {dtabL[bu + j8], dtabL[bu + j8 + 1], dtabL[bu + j8 + 2], dtabL[bu + j8 + 3]};
            f4 o1 = {dtabL[bu + j8 + 4], dtabL[bu + j8 + 5], dtabL[bu + j8 + 6],
                     dtabL[bu + j8 + 7]};
            const size_t rb = ((size_t)h * SQ + r) * SQ + j8;
            __builtin_nontemporal_store(o0, (f4*)&pbp[rb]);
            __builtin_nontemporal_store(o1, (f4*)&pbp[rb + 4]);
        }
        __syncthreads();
    }
    float sinv[2];
#pragma unroll
    for (int isub = 0; isub < 2; ++isub) {
        float s = srow[isub];
        s += __shfl_xor(s, 16);
        s += __shfl_xor(s, 32);
        sinv[isub] = 1.0f / s;
    }

    // ---- pass 2: recompute, nt f4 attw writes, LDS-P, PV --------------------
    f4 o[4][2];
#pragma unroll
    for (int ns = 0; ns < 4; ++ns)
#pragma unroll
        for (int isub = 0; isub < 2; ++isub) o[ns][isub] = (f4){0.f, 0.f, 0.f, 0.f};
    const size_t awb = (size_t)bh * ((size_t)SQ * SQ);
    char* Pw = Psm + w * 4096;

    for (int t = 0; t < 32; ++t) {
        const int j0 = t * 64;
        stageK(j0);
        stageV(j0);
        __syncthreads();
        f4 a[4][2];
#pragma unroll
        for (int ns = 0; ns < 4; ++ns) {
            const int rr = ns * 16 + (lane & 15);
            const int kc = lane >> 4;
            h8 kf0 = *(const h8*)&Kl[rr * 64 + ((kc ^ (rr & 7)) * 8)];
            h8 kf1 = *(const h8*)&Kl[rr * 64 + (((kc + 4) ^ (rr & 7)) * 8)];
#pragma unroll
            for (int isub = 0; isub < 2; ++isub) {
                f4 z = (f4){0.f, 0.f, 0.f, 0.f};
                z = __builtin_amdgcn_mfma_f32_16x16x32_f16(kf0, qf[isub][0], z, 0, 0, 0);
                z = __builtin_amdgcn_mfma_f32_16x16x32_f16(kf1, qf[isub][1], z, 0, 0, 0);
                a[ns][isub] = z;
            }
        }
#pragma unroll
        for (int ns = 0; ns < 4; ++ns)
#pragma unroll
            for (int isub = 0; isub < 2; ++isub) {
                const int wloc = w * 32 + isub * 16 + (lane & 15);
                const int jbase = ns * 16 + ((lane >> 4) << 2);
                const int u0 = j0 + jbase - (i0 + wloc) + 2047;
                f4 p;
#pragma unroll
                for (int reg = 0; reg < 4; ++reg)
                    p[reg] = __expf(a[ns][isub][reg] + dtabL[u0 + reg]) * sinv[isub];
                __builtin_nontemporal_store(
                    p, (f4*)&attw[awb + (size_t)(i0 + wloc) * SQ + j0 + jbase]);
                const int iloc = isub * 16 + (lane & 15);
                h4 ph = {(half_t)p[0], (half_t)p[1], (half_t)p[2], (half_t)p[3]};
                *(h4*)&Pw[iloc * 128 + (((jbase >> 3) ^ (iloc & 7)) << 4) + ((jbase & 4) << 1)] = ph;
            }
        h8 pf[2][2];
#pragma unroll
        for (int isub = 0; isub < 2; ++isub) {
            const int iloc = isub * 16 + (lane & 15);
            pf[isub][0] = *(const h8*)&Pw[iloc * 128 + (((lane >> 4) ^ (iloc & 7)) << 4)];
            pf[isub][1] = *(const h8*)&Pw[iloc * 128 + ((((lane >> 4) + 4) ^ (iloc & 7)) << 4)];
        }
#pragma unroll
        for (int ns = 0; ns < 4; ++ns) {
            const int rr = ns * 16 + (lane & 15);
            const int kc = lane >> 4;
            h8 vf0 = *(const h8*)&Vl[rr * 64 + ((kc ^ (rr & 7)) * 8)];
            h8 vf1 = *(const h8*)&Vl[rr * 64 + (((kc + 4) ^ (rr & 7)) * 8)];
#pragma unroll
            for (int isub = 0; isub < 2; ++isub) {
                o[ns][isub] =
                    __builtin_amdgcn_mfma_f32_16x16x32_f16(pf[isub][0], vf0, o[ns][isub], 0, 0, 0);
                o[ns][isub] =
                    __builtin_amdgcn_mfma_f32_16x16x32_f16(pf[isub][1], vf1, o[ns][isub], 0, 0, 0);
            }
        }
        __syncthreads();
    }
#pragma unroll
    for (int ns = 0; ns < 4; ++ns)
#pragma unroll
        for (int isub = 0; isub < 2; ++isub)
#pragma unroll
            for (int reg = 0; reg < 4; ++reg) {
                int row = i0 + w * 32 + isub * 16 + (lane >> 4) * 4 + reg;
                int d = ns * 16 + (lane & 15);
                ctx[((size_t)(b * SQ + row)) * DM + h * HD + d] = (half_t)o[ns][isub][reg];
            }
}

// ---- standalone bias fill (fallback ordering path only) ---------------------
__global__ __launch_bounds__(256) void bias_fill(const float* __restrict__ dtab,
                                                 float* __restrict__ pb) {
    __shared__ float L[2052];
    const int i = blockIdx.x, h = blockIdx.y;
    const int s0 = 2047 - i, a0 = s0 & ~3, sh = s0 - a0;
    for (int t = threadIdx.x * 4; t < 2052; t += 1024)
        *(f4*)&L[t] = *(const f4*)&dtab[h * 4096 + a0 + t];
    __syncthreads();
    const size_t base = ((size_t)h * SQ + i) * SQ;
#pragma unroll
    for (int half = 0; half < 2; ++half) {
        int j = half * 1024 + threadIdx.x * 4;
        f4 o = {L[sh + j], L[sh + j + 1], L[sh + j + 2], L[sh + j + 3]};
        __builtin_nontemporal_store(o, (f4*)&pb[base + j]);
    }
}

extern "C" void kernel_launch(void* const* d_in, const int* in_sizes, int n_in, void* d_out,
                              int out_size, void* d_ws, size_t ws_size, hipStream_t stream) {
    const float* X = (const float*)d_in[0];
    const float* Wq = (const float*)d_in[1];
    const float* Wk = (const float*)d_in[2];
    const float* Wv = (const float*)d_in[3];
    const float* Wo = (const float*)d_in[4];
    const float* tbl = (const float*)d_in[5];

    float* out = (float*)d_out;
    float* attn_out = out;                    // 8,388,608 f32
    float* pb = out + (size_t)NB * SQ * DM;   // 67,108,864 f32
    float* attw = pb + (size_t)NH * SQ * SQ;  // 268,435,456 f32

    // f16 scratch: prefer d_ws; fall back to pb region (bias fill must run LAST then)
    const size_t need_bytes = 109314048;
    const bool ws_ok = (ws_size >= need_bytes);
    half_t* hb = ws_ok ? (half_t*)d_ws : (half_t*)pb;
    half_t* Xh = hb;
    half_t* qh = hb + 8388608;
    half_t* kh = hb + 16777216;
    half_t* vTh = hb + 33554432;
    half_t* ctxh = hb + 41943040;
    half_t* Wqt = hb + 50331648;
    half_t* Wkt = hb + 51380224;
    half_t* Wvt = hb + 52428800;
    half_t* Wot = hb + 53477376;
    float* dtab = (float*)(hb + 54525952);  // 16 x 4096 f32

    dim3 blk(256);
    prep<<<dim3(5136), blk, 0, stream>>>(X, Wq, Wk, Wv, Wo, tbl, Xh, Wqt, Wkt, Wvt, Wot, dtab);
    mm_qkv<<<dim3(8, 64, 3), blk, 0, stream>>>(Xh, Wqt, Wkt, Wvt, qh, kh, vTh);
    fused_attn<<<dim3(1024), blk, 0, stream>>>(qh, kh, vTh, dtab, attw, ctxh,
                                               ws_ok ? pb : (float*)nullptr);
    mm_wo<<<dim3(8, 64), blk, 0, stream>>>(ctxh, Wot, attn_out);
    if (!ws_ok) bias_fill<<<dim3(SQ, NH), blk, 0, stream>>>(dtab, pb);
}

// Round 10
// 549.579 us; speedup vs baseline: 1.7338x; 1.0807x over previous
//
#include <hip/hip_runtime.h>
#include <cstdint>
#include <cmath>

#define NH 16
#define HD 64
#define SQ 2048
#define NB 4
#define DM 1024

typedef _Float16 half_t;
typedef _Float16 h8 __attribute__((ext_vector_type(8)));
typedef _Float16 h4 __attribute__((ext_vector_type(4)));
typedef float f4 __attribute__((ext_vector_type(4)));

// bucket(delta) per MT5 relative_position_bucket (bidirectional, 32 buckets, max_dist 128)
__device__ __forceinline__ int rel_bucket(int delta) {
    int b = (delta > 0) ? 16 : 0;
    int a = (delta < 0) ? -delta : delta;
    if (a < 8) return b + a;
    int large = 8 + (int)(__logf((float)a * 0.125f) * 2.8853900817779268f);
    return b + (large < 15 ? large : 15);
}

// async global->LDS, 16B per lane; LDS dest = wave-uniform base + lane*16
__device__ __forceinline__ void gl_lds(const half_t* g, half_t* l) {
    __builtin_amdgcn_global_load_lds((const __attribute__((address_space(1))) unsigned int*)g,
                                     (__attribute__((address_space(3))) unsigned int*)l, 16, 0, 0);
}

// ---- prep: X f32->f16 (0..4095) + W transposes (4096..5119) + dtab (5120..5135)
__global__ __launch_bounds__(256) void prep(const float* __restrict__ X,
                                            const float* __restrict__ Wq,
                                            const float* __restrict__ Wk,
                                            const float* __restrict__ Wv,
                                            const float* __restrict__ Wo,
                                            const float* __restrict__ table,
                                            half_t* __restrict__ Xh, half_t* __restrict__ Wqt,
                                            half_t* __restrict__ Wkt, half_t* __restrict__ Wvt,
                                            half_t* __restrict__ Wot, float* __restrict__ dtab) {
    const int id = blockIdx.x;
    if (id < 4096) {
        size_t i = ((size_t)id * 256 + threadIdx.x) * 8;
        float4 a = *(const float4*)&X[i];
        float4 b = *(const float4*)&X[i + 4];
        half_t t[8] = {(half_t)a.x, (half_t)a.y, (half_t)a.z, (half_t)a.w,
                       (half_t)b.x, (half_t)b.y, (half_t)b.z, (half_t)b.w};
        *(h8*)&Xh[i] = *(h8*)t;
        return;
    }
    if (id >= 5120) {
        const int h = id - 5120;  // dtab[h][d] = bias(delta = d - 2047) for head h
        for (int d = threadIdx.x; d < 4096; d += 256)
            dtab[h * 4096 + d] = table[rel_bucket(d - 2047) * NH + h];
        return;
    }
    __shared__ float T[64][65];
    const int t = id - 4096;
    const int which = t >> 8, tile = t & 255;
    const float* W = which == 0 ? Wq : which == 1 ? Wk : which == 2 ? Wv : Wo;
    half_t* Wt = which == 0 ? Wqt : which == 1 ? Wkt : which == 2 ? Wvt : Wot;
    const int k0 = (tile >> 4) * 64, n0 = (tile & 15) * 64;
    const int c = threadIdx.x & 63, rr = threadIdx.x >> 6;
    for (int r = rr; r < 64; r += 4) T[r][c] = W[(size_t)(k0 + r) * DM + n0 + c];
    __syncthreads();
    for (int r = rr; r < 64; r += 4) Wt[(size_t)(n0 + r) * DM + k0 + c] = (half_t)T[c][r];
}

// ---- v[bh][s][d] f16 -> vT[bh][d][s] f16 (coalesced) ------------------------
__global__ __launch_bounds__(256) void transpose_v(const half_t* __restrict__ v,
                                                   half_t* __restrict__ vT) {
    __shared__ half_t T[64][72];
    const int bh = blockIdx.y, j0 = blockIdx.x * 64;
    const size_t base = (size_t)bh * (SQ * HD);
    const int t = threadIdx.x;
    for (int e = t; e < 512; e += 256) {
        int r = e >> 3, c = e & 7;
        *(h8*)&T[r][c * 8] = *(const h8*)&v[base + (size_t)(j0 + r) * HD + c * 8];
    }
    __syncthreads();
    const int d = t & 63, jc = t >> 6;
    half_t tmp[16];
#pragma unroll
    for (int jj = 0; jj < 16; ++jj) tmp[jj] = T[jc * 16 + jj][d];
    *(h8*)&vT[base + (size_t)d * SQ + j0 + jc * 16] = *(h8*)&tmp[0];
    *(h8*)&vT[base + (size_t)d * SQ + j0 + jc * 16 + 8] = *(h8*)&tmp[8];
}

// ---- QKV MFMA GEMM: dbuf LDS, swapped-operand epilogue (reg dim = n) --------
__global__ __launch_bounds__(256) void mm_qkv(const half_t* __restrict__ A,
                                              const half_t* __restrict__ Wqt,
                                              const half_t* __restrict__ Wkt,
                                              const half_t* __restrict__ Wvt,
                                              half_t* __restrict__ qo, half_t* __restrict__ ko,
                                              half_t* __restrict__ vo) {
    const int z = blockIdx.z;
    const half_t* Bt = z == 0 ? Wqt : z == 1 ? Wkt : Wvt;
    half_t* outp = z == 0 ? qo : z == 1 ? ko : vo;
    __shared__ half_t Al[2][4096];
    __shared__ half_t Bl[2][4096];
    const int tid = threadIdx.x;
    const int lane = tid & 63, w = tid >> 6;
    const int wr = w >> 1, wc = w & 1;
    const int id0 = blockIdx.y * 8 + blockIdx.x;
    const int swz = (id0 & 7) * 64 + (id0 >> 3);
    const int m0 = (swz >> 3) * 128, n0 = (swz & 7) * 128;

    f4 acc[4][4];
#pragma unroll
    for (int i = 0; i < 4; ++i)
#pragma unroll
        for (int j = 0; j < 4; ++j) acc[i][j] = (f4){0.f, 0.f, 0.f, 0.f};

    const int kc = lane >> 4;
    const int srl = lane >> 2;
    const int sc = lane & 3;

    auto stage = [&](int buf, int k0) {
#pragma unroll
        for (int inst = 0; inst < 2; ++inst) {
            int r = w * 32 + inst * 16 + srl;
            int cg = sc ^ ((r >> 1) & 3);
            gl_lds(&A[(size_t)(m0 + r) * DM + k0 + cg * 8], &Al[buf][(w * 32 + inst * 16) * 32]);
            gl_lds(&Bt[(size_t)(n0 + r) * DM + k0 + cg * 8], &Bl[buf][(w * 32 + inst * 16) * 32]);
        }
    };

    stage(0, 0);
    __syncthreads();
    int cur = 0;
    for (int t = 0; t < 32; ++t) {
        if (t < 31) stage(cur ^ 1, (t + 1) * 32);
        h8 af[4], bf[4];
#pragma unroll
        for (int ms = 0; ms < 4; ++ms) {
            int r = wr * 64 + ms * 16 + (lane & 15);
            af[ms] = *(const h8*)&Al[cur][r * 32 + ((kc ^ ((r >> 1) & 3)) * 8)];
        }
#pragma unroll
        for (int ns = 0; ns < 4; ++ns) {
            int r = wc * 64 + ns * 16 + (lane & 15);
            bf[ns] = *(const h8*)&Bl[cur][r * 32 + ((kc ^ ((r >> 1) & 3)) * 8)];
        }
        // swapped operands: C col (lane&15) = m, reg dim = n
#pragma unroll
        for (int ms = 0; ms < 4; ++ms)
#pragma unroll
            for (int ns = 0; ns < 4; ++ns)
                acc[ms][ns] =
                    __builtin_amdgcn_mfma_f32_16x16x32_f16(bf[ns], af[ms], acc[ms][ns], 0, 0, 0);
        __syncthreads();
        cur ^= 1;
    }

#pragma unroll
    for (int ms = 0; ms < 4; ++ms)
#pragma unroll
        for (int ns = 0; ns < 4; ++ns) {
            int m = m0 + wr * 64 + ms * 16 + (lane & 15);
            int nb = n0 + wc * 64 + ns * 16 + ((lane >> 4) << 2);
            int b = m >> 11, s = m & 2047, h = nb >> 6, d = nb & 63;
            h4 ph = {(half_t)acc[ms][ns][0], (half_t)acc[ms][ns][1], (half_t)acc[ms][ns][2],
                     (half_t)acc[ms][ns][3]};
            *(h4*)&outp[((size_t)(b * NH + h) * SQ + s) * HD + d] = ph;
        }
}

// ---- Wo GEMM: dbuf LDS, swapped-operand epilogue, f4 nt stores --------------
__global__ __launch_bounds__(256) void mm_wo(const half_t* __restrict__ A,
                                             const half_t* __restrict__ Bt,
                                             float* __restrict__ outp) {
    __shared__ half_t Al[2][4096];
    __shared__ half_t Bl[2][4096];
    const int tid = threadIdx.x;
    const int lane = tid & 63, w = tid >> 6;
    const int wr = w >> 1, wc = w & 1;
    const int id0 = blockIdx.y * 8 + blockIdx.x;
    const int swz = (id0 & 7) * 64 + (id0 >> 3);
    const int m0 = (swz >> 3) * 128, n0 = (swz & 7) * 128;

    f4 acc[4][4];
#pragma unroll
    for (int i = 0; i < 4; ++i)
#pragma unroll
        for (int j = 0; j < 4; ++j) acc[i][j] = (f4){0.f, 0.f, 0.f, 0.f};

    const int kc = lane >> 4;
    const int srl = lane >> 2;
    const int sc = lane & 3;

    auto stage = [&](int buf, int k0) {
#pragma unroll
        for (int inst = 0; inst < 2; ++inst) {
            int r = w * 32 + inst * 16 + srl;
            int cg = sc ^ ((r >> 1) & 3);
            gl_lds(&A[(size_t)(m0 + r) * DM + k0 + cg * 8], &Al[buf][(w * 32 + inst * 16) * 32]);
            gl_lds(&Bt[(size_t)(n0 + r) * DM + k0 + cg * 8], &Bl[buf][(w * 32 + inst * 16) * 32]);
        }
    };

    stage(0, 0);
    __syncthreads();
    int cur = 0;
    for (int t = 0; t < 32; ++t) {
        if (t < 31) stage(cur ^ 1, (t + 1) * 32);
        h8 af[4], bf[4];
#pragma unroll
        for (int ms = 0; ms < 4; ++ms) {
            int r = wr * 64 + ms * 16 + (lane & 15);
            af[ms] = *(const h8*)&Al[cur][r * 32 + ((kc ^ ((r >> 1) & 3)) * 8)];
        }
#pragma unroll
        for (int ns = 0; ns < 4; ++ns) {
            int r = wc * 64 + ns * 16 + (lane & 15);
            bf[ns] = *(const h8*)&Bl[cur][r * 32 + ((kc ^ ((r >> 1) & 3)) * 8)];
        }
#pragma unroll
        for (int ms = 0; ms < 4; ++ms)
#pragma unroll
            for (int ns = 0; ns < 4; ++ns)
                acc[ms][ns] =
                    __builtin_amdgcn_mfma_f32_16x16x32_f16(bf[ns], af[ms], acc[ms][ns], 0, 0, 0);
        __syncthreads();
        cur ^= 1;
    }

#pragma unroll
    for (int ms = 0; ms < 4; ++ms)
#pragma unroll
        for (int ns = 0; ns < 4; ++ns) {
            int m = m0 + wr * 64 + ms * 16 + (lane & 15);
            int nb = n0 + wc * 64 + ns * 16 + ((lane >> 4) << 2);
            __builtin_nontemporal_store(acc[ms][ns], (f4*)&outp[(size_t)m * DM + nb]);
        }
}

// ---- fused attention: R6 structure + exp-fusion + hidden pb stream ----------
// block = 128 q-rows of one (b,h); 4 waves x 32 rows; LDS 64 KB -> 2 blocks/CU.
template <bool PB>
__global__ __launch_bounds__(256) void fused_attn(const half_t* __restrict__ q,
                                                  const half_t* __restrict__ k,
                                                  const half_t* __restrict__ vT,
                                                  const float* __restrict__ dtab,
                                                  float* __restrict__ attw,
                                                  half_t* __restrict__ ctx,
                                                  float* __restrict__ pbp) {
    __shared__ float dtabL[4096];   // raw bias(delta), idx u = j - i + 2047
    __shared__ char Psm[16384];     // per-wave 4KB: P[32 i][64 j] f16, 16B-slot XOR swizzle
    __shared__ half_t Kl[2][4096];  // K tile dbuf: slot s of row r = chunk s^(r&7)
    __shared__ half_t Vl[2][4096];  // V^T tile dbuf: same swizzle
    const int tid = threadIdx.x, lane = tid & 63, w = tid >> 6;

    // XCD-bijective swizzle: each bh's 16 blocks on one XCD
    const int id = blockIdx.x;
    const int idx = (id & 7) * 128 + (id >> 3);
    const int bh = idx >> 4, i0 = (idx & 15) * 128;
    const int h = bh & 15, b = bh >> 4;
    const size_t qb = (size_t)bh * (SQ * HD);
    const half_t* kb = k + qb;
    const half_t* vb = vT + qb;

    for (int t = tid * 4; t < 4096; t += 1024)
        *(f4*)&dtabL[t] = *(const f4*)&dtab[h * 4096 + t];

    h8 qf[2][2];
#pragma unroll
    for (int isub = 0; isub < 2; ++isub) {
        const half_t* qp =
            &q[qb + (size_t)(i0 + w * 32 + isub * 16 + (lane & 15)) * HD + (lane >> 4) * 8];
        qf[isub][0] = *(const h8*)qp;
        qf[isub][1] = *(const h8*)(qp + 32);
    }

    const int sr = lane >> 3;  // staging row within 8-row group
    const int sc = lane & 7;   // LDS slot

    auto stageK = [&](int buf, int j0) {
#pragma unroll
        for (int inst = 0; inst < 2; ++inst) {
            int r = w * 16 + inst * 8 + sr;
            gl_lds(&kb[(size_t)(j0 + r) * HD + ((sc ^ (r & 7)) * 8)],
                   &Kl[buf][(w * 16 + inst * 8) * 64]);
        }
    };
    auto stageV = [&](int buf, int j0) {
#pragma unroll
        for (int inst = 0; inst < 2; ++inst) {
            int r = w * 16 + inst * 8 + sr;
            gl_lds(&vb[(size_t)r * SQ + j0 + ((sc ^ (r & 7)) * 8)],
                   &Vl[buf][(w * 16 + inst * 8) * 64]);
        }
    };

    // ---- pass 1: row sums of exp(score + bias); pb rows hidden here ---------
    stageK(0, 0);
    __syncthreads();
    float srow[2] = {0.f, 0.f};
    int cur = 0;
    for (int t = 0; t < 32; ++t) {
        const int j0 = t * 64;
        if (t < 31) stageK(cur ^ 1, j0 + 64);  // 2 loads (oldest vmem this iter)
        if (PB) {
            __builtin_amdgcn_sched_barrier(0);  // pin loads before pb stores
            const int r = i0 + b * 32 + t;      // exact cover of rows per h
            const int bu = 2047 - r;
            const int j8 = tid * 8;
            f4 o0 = {dtabL[bu + j8], dtabL[bu + j8 + 1], dtabL[bu + j8 + 2], dtabL[bu + j8 + 3]};
            f4 o1 = {dtabL[bu + j8 + 4], dtabL[bu + j8 + 5], dtabL[bu + j8 + 6],
                     dtabL[bu + j8 + 7]};
            const size_t rb = ((size_t)h * SQ + r) * SQ + j8;
            __builtin_nontemporal_store(o0, (f4*)&pbp[rb]);
            __builtin_nontemporal_store(o1, (f4*)&pbp[rb + 4]);
            __builtin_amdgcn_sched_barrier(0);
        }
#pragma unroll
        for (int ns = 0; ns < 4; ++ns) {
            const int rr = ns * 16 + (lane & 15);
            const int kc = lane >> 4;
            h8 kf0 = *(const h8*)&Kl[cur][rr * 64 + ((kc ^ (rr & 7)) * 8)];
            h8 kf1 = *(const h8*)&Kl[cur][rr * 64 + (((kc + 4) ^ (rr & 7)) * 8)];
#pragma unroll
            for (int isub = 0; isub < 2; ++isub) {
                f4 z = (f4){0.f, 0.f, 0.f, 0.f};
                z = __builtin_amdgcn_mfma_f32_16x16x32_f16(kf0, qf[isub][0], z, 0, 0, 0);
                z = __builtin_amdgcn_mfma_f32_16x16x32_f16(kf1, qf[isub][1], z, 0, 0, 0);
                const int u0 = j0 + ns * 16 + ((lane >> 4) << 2) -
                               (i0 + w * 32 + isub * 16 + (lane & 15)) + 2047;
#pragma unroll
                for (int reg = 0; reg < 4; ++reg)
                    srow[isub] += __expf(z[reg] + dtabL[u0 + reg]);
            }
        }
        if (PB) {
            // loads retire (oldest); the 2 newest (pb stores) stay in flight
            asm volatile("s_waitcnt vmcnt(2)" ::: "memory");
            __builtin_amdgcn_s_barrier();
            __builtin_amdgcn_sched_barrier(0);
        } else {
            __syncthreads();
        }
        cur ^= 1;
    }
    float sinv[2];
#pragma unroll
    for (int isub = 0; isub < 2; ++isub) {
        float s = srow[isub];
        s += __shfl_xor(s, 16);
        s += __shfl_xor(s, 32);
        sinv[isub] = 1.0f / s;
    }

    // ---- pass 2: recompute, nt f4 attw writes, LDS-P, PV; counted vmcnt -----
    f4 o[4][2];
#pragma unroll
    for (int ns = 0; ns < 4; ++ns)
#pragma unroll
        for (int isub = 0; isub < 2; ++isub) o[ns][isub] = (f4){0.f, 0.f, 0.f, 0.f};
    const size_t awb = (size_t)bh * ((size_t)SQ * SQ);
    char* Pw = Psm + w * 4096;

    stageK(0, 0);
    stageV(0, 0);
    __syncthreads();
    cur = 0;
    for (int t = 0; t < 32; ++t) {
        const int j0 = t * 64;
        if (t < 31) {
            stageK(cur ^ 1, j0 + 64);
            stageV(cur ^ 1, j0 + 64);
        }
        __builtin_amdgcn_sched_barrier(0);  // pin: staging loads issue before attw stores
        f4 a[4][2];
#pragma unroll
        for (int ns = 0; ns < 4; ++ns) {
            const int rr = ns * 16 + (lane & 15);
            const int kc = lane >> 4;
            h8 kf0 = *(const h8*)&Kl[cur][rr * 64 + ((kc ^ (rr & 7)) * 8)];
            h8 kf1 = *(const h8*)&Kl[cur][rr * 64 + (((kc + 4) ^ (rr & 7)) * 8)];
#pragma unroll
            for (int isub = 0; isub < 2; ++isub) {
                f4 z = (f4){0.f, 0.f, 0.f, 0.f};
                z = __builtin_amdgcn_mfma_f32_16x16x32_f16(kf0, qf[isub][0], z, 0, 0, 0);
                z = __builtin_amdgcn_mfma_f32_16x16x32_f16(kf1, qf[isub][1], z, 0, 0, 0);
                a[ns][isub] = z;
            }
        }
#pragma unroll
        for (int ns = 0; ns < 4; ++ns)
#pragma unroll
            for (int isub = 0; isub < 2; ++isub) {
                const int wloc = w * 32 + isub * 16 + (lane & 15);
                const int jbase = ns * 16 + ((lane >> 4) << 2);
                const int u0 = j0 + jbase - (i0 + wloc) + 2047;
                f4 p;
#pragma unroll
                for (int reg = 0; reg < 4; ++reg)
                    p[reg] = __expf(a[ns][isub][reg] + dtabL[u0 + reg]) * sinv[isub];
                __builtin_nontemporal_store(
                    p, (f4*)&attw[awb + (size_t)(i0 + wloc) * SQ + j0 + jbase]);
                const int iloc = isub * 16 + (lane & 15);
                h4 ph = {(half_t)p[0], (half_t)p[1], (half_t)p[2], (half_t)p[3]};
                *(h4*)&Pw[iloc * 128 + (((jbase >> 3) ^ (iloc & 7)) << 4) + ((jbase & 4) << 1)] = ph;
            }
        h8 pf[2][2];
#pragma unroll
        for (int isub = 0; isub < 2; ++isub) {
            const int iloc = isub * 16 + (lane & 15);
            pf[isub][0] = *(const h8*)&Pw[iloc * 128 + (((lane >> 4) ^ (iloc & 7)) << 4)];
            pf[isub][1] = *(const h8*)&Pw[iloc * 128 + ((((lane >> 4) + 4) ^ (iloc & 7)) << 4)];
        }
#pragma unroll
        for (int ns = 0; ns < 4; ++ns) {
            const int rr = ns * 16 + (lane & 15);
            const int kc = lane >> 4;
            h8 vf0 = *(const h8*)&Vl[cur][rr * 64 + ((kc ^ (rr & 7)) * 8)];
            h8 vf1 = *(const h8*)&Vl[cur][rr * 64 + (((kc + 4) ^ (rr & 7)) * 8)];
#pragma unroll
            for (int isub = 0; isub < 2; ++isub) {
                o[ns][isub] =
                    __builtin_amdgcn_mfma_f32_16x16x32_f16(pf[isub][0], vf0, o[ns][isub], 0, 0, 0);
                o[ns][isub] =
                    __builtin_amdgcn_mfma_f32_16x16x32_f16(pf[isub][1], vf1, o[ns][isub], 0, 0, 0);
            }
        }
        // 4 staging loads are oldest; 8 nt attw stores may stay in flight
        asm volatile("s_waitcnt vmcnt(8)" ::: "memory");
        __builtin_amdgcn_s_barrier();
        __builtin_amdgcn_sched_barrier(0);
        cur ^= 1;
    }
#pragma unroll
    for (int ns = 0; ns < 4; ++ns)
#pragma unroll
        for (int isub = 0; isub < 2; ++isub)
#pragma unroll
            for (int reg = 0; reg < 4; ++reg) {
                int row = i0 + w * 32 + isub * 16 + (lane >> 4) * 4 + reg;
                int d = ns * 16 + (lane & 15);
                ctx[((size_t)(b * SQ + row)) * DM + h * HD + d] = (half_t)o[ns][isub][reg];
            }
}

// ---- standalone bias fill (fallback ordering path only) ---------------------
__global__ __launch_bounds__(256) void bias_fill(const float* __restrict__ dtab,
                                                 float* __restrict__ pb) {
    __shared__ float L[2052];
    const int i = blockIdx.x, h = blockIdx.y;
    const int s0 = 2047 - i, a0 = s0 & ~3, sh = s0 - a0;
    for (int t = threadIdx.x * 4; t < 2052; t += 1024)
        *(f4*)&L[t] = *(const f4*)&dtab[h * 4096 + a0 + t];
    __syncthreads();
    const size_t base = ((size_t)h * SQ + i) * SQ;
#pragma unroll
    for (int half = 0; half < 2; ++half) {
        int j = half * 1024 + threadIdx.x * 4;
        f4 o = {L[sh + j], L[sh + j + 1], L[sh + j + 2], L[sh + j + 3]};
        __builtin_nontemporal_store(o, (f4*)&pb[base + j]);
    }
}

extern "C" void kernel_launch(void* const* d_in, const int* in_sizes, int n_in, void* d_out,
                              int out_size, void* d_ws, size_t ws_size, hipStream_t stream) {
    const float* X = (const float*)d_in[0];
    const float* Wq = (const float*)d_in[1];
    const float* Wk = (const float*)d_in[2];
    const float* Wv = (const float*)d_in[3];
    const float* Wo = (const float*)d_in[4];
    const float* tbl = (const float*)d_in[5];

    float* out = (float*)d_out;
    float* attn_out = out;                    // 8,388,608 f32
    float* pb = out + (size_t)NB * SQ * DM;   // 67,108,864 f32
    float* attw = pb + (size_t)NH * SQ * SQ;  // 268,435,456 f32

    // f16 scratch: prefer d_ws; fall back to pb region (bias fill runs LAST then)
    const size_t need_bytes = 109314048;
    const bool ws_ok = (ws_size >= need_bytes);
    half_t* hb = ws_ok ? (half_t*)d_ws : (half_t*)pb;
    half_t* Xh = hb;
    half_t* qh = hb + 8388608;
    half_t* kh = hb + 16777216;
    half_t* vh = hb + 25165824;
    half_t* vTh = hb + 33554432;
    half_t* ctxh = hb + 41943040;
    half_t* Wqt = hb + 50331648;
    half_t* Wkt = hb + 51380224;
    half_t* Wvt = hb + 52428800;
    half_t* Wot = hb + 53477376;
    float* dtab = (float*)(hb + 54525952);  // 16 x 4096 f32

    dim3 blk(256);
    prep<<<dim3(5136), blk, 0, stream>>>(X, Wq, Wk, Wv, Wo, tbl, Xh, Wqt, Wkt, Wvt, Wot, dtab);
    mm_qkv<<<dim3(8, 64, 3), blk, 0, stream>>>(Xh, Wqt, Wkt, Wvt, qh, kh, vh);
    transpose_v<<<dim3(32, 64), blk, 0, stream>>>(vh, vTh);
    if (ws_ok) {
        fused_attn<true><<<dim3(1024), blk, 0, stream>>>(qh, kh, vTh, dtab, attw, ctxh, pb);
        mm_wo<<<dim3(8, 64), blk, 0, stream>>>(ctxh, Wot, attn_out);
    } else {
        fused_attn<false><<<dim3(1024), blk, 0, stream>>>(qh, kh, vTh, dtab, attw, ctxh, nullptr);
        mm_wo<<<dim3(8, 64), blk, 0, stream>>>(ctxh, Wot, attn_out);
        bias_fill<<<dim3(SQ, NH), blk, 0, stream>>>(dtab, pb);
    }
}